// Round 23
// baseline (197.627 us; speedup 1.0000x reference)
//
#include <hip/hip_runtime.h>
#include <hip/hip_cooperative_groups.h>
#include <math.h>

#define BB 4
#define NN 2048
#define CIN 64
#define HID 128
#define HEADS 4
#define NQ 16
#define KTOT (NN*HID) // 262144
#define LOG2E 1.44269504088896340736f
#define NSL 4         // j-slices (512 j each)
#define GRID 512
#define HB 512        // fallback k_pre blocks doing hidden
#define AB 2048       // fallback k_pre blocks doing adj bitmask

typedef __attribute__((ext_vector_type(8))) _Float16 half8;
typedef __attribute__((ext_vector_type(4))) float f32x4;
typedef __attribute__((ext_vector_type(4))) unsigned uint4v;

namespace cg = cooperative_groups;

// ===================== shared device helpers =====================
__device__ __forceinline__ half8 makeaf_fac(float es, float es5, unsigned bits,
                                            const float* edv, const float* ed5v)
{
    float wv[8];
#pragma unroll
    for (int e = 0; e < 8; ++e) {
        const float wp = es * edv[e];
        const float wn = es5 * ed5v[e];
        const float w = fmaxf(wp, wn);                        // = exp(lrelu(s))
        const unsigned m = (unsigned)(((int)(bits << (31 - e))) >> 31);
        wv[e] = __builtin_bit_cast(float, __builtin_bit_cast(unsigned, w) & m);
    }
    uint4v uu;
    uu[0] = __builtin_bit_cast(unsigned, __builtin_amdgcn_cvt_pkrtz(wv[0], wv[1]));
    uu[1] = __builtin_bit_cast(unsigned, __builtin_amdgcn_cvt_pkrtz(wv[2], wv[3]));
    uu[2] = __builtin_bit_cast(unsigned, __builtin_amdgcn_cvt_pkrtz(wv[4], wv[5]));
    uu[3] = __builtin_bit_cast(unsigned, __builtin_amdgcn_cvt_pkrtz(wv[6], wv[7]));
    return __builtin_bit_cast(half8, uu);
}

// Phase-B body for one virtual block id (R21 k_attn config)
__device__ __forceinline__ void attn_body(
    int vb, int t, const unsigned* __restrict__ adjT, const _Float16* __restrict__ hHT,
    const float* __restrict__ EsA, const float* __restrict__ Es5A,
    const float* __restrict__ EdA, const float* __restrict__ Ed5A,
    _Float16* __restrict__ P, float* __restrict__ S)
{
    const int lane = t & 63;
    const int h = t >> 6;
    const int iq = vb & 63;
    const int b = (vb >> 6) & 3;
    const int jq = vb >> 8;
    const int i0 = iq * 32;
    const int jb0 = jq * 16;

    const int r16 = lane & 15;
    const int g = lane >> 4;

    const size_t abase = (size_t)(b * HEADS + h) * NN;
    const float es0  = EsA [abase + i0 + r16];
    const float es05 = Es5A[abase + i0 + r16];
    const float es1  = EsA [abase + i0 + 16 + r16];
    const float es15 = Es5A[abase + i0 + 16 + r16];
    const unsigned* adjr0 = adjT + (size_t)jb0 * NN + i0 + r16;
    const unsigned* adjr1 = adjr0 + 16;
    const _Float16* hb = hHT + (size_t)b * KTOT + (size_t)jb0 * 4096
                             + (h * 32 + r16) * 32 + g * 8;
    const float4* ed4  = (const float4*)(EdA  + abase + jq * 512) + 2 * g;
    const float4* ed54 = (const float4*)(Ed5A + abase + jq * 512) + 2 * g;

    f32x4 acc00 = {0.f, 0.f, 0.f, 0.f};
    f32x4 acc01 = {0.f, 0.f, 0.f, 0.f};
    f32x4 acc10 = {0.f, 0.f, 0.f, 0.f};
    f32x4 acc11 = {0.f, 0.f, 0.f, 0.f};
    f32x4 accS0 = {0.f, 0.f, 0.f, 0.f};
    f32x4 accS1 = {0.f, 0.f, 0.f, 0.f};
    const half8 ones = {(_Float16)1.f, (_Float16)1.f, (_Float16)1.f, (_Float16)1.f,
                        (_Float16)1.f, (_Float16)1.f, (_Float16)1.f, (_Float16)1.f};

    auto COMPUTE = [&](unsigned w0, unsigned w1, half8 bb0, half8 bb1,
                       float4 e0, float4 e1, float4 f0, float4 f1) {
        const float edv[8]  = {e0.x, e0.y, e0.z, e0.w, e1.x, e1.y, e1.z, e1.w};
        const float ed5v[8] = {f0.x, f0.y, f0.z, f0.w, f1.x, f1.y, f1.z, f1.w};
        const half8 af0 = makeaf_fac(es0, es05, w0 >> (8 * g), edv, ed5v);
        const half8 af1 = makeaf_fac(es1, es15, w1 >> (8 * g), edv, ed5v);
        acc00 = __builtin_amdgcn_mfma_f32_16x16x32_f16(af0, bb0, acc00, 0, 0, 0);
        acc01 = __builtin_amdgcn_mfma_f32_16x16x32_f16(af0, bb1, acc01, 0, 0, 0);
        accS0 = __builtin_amdgcn_mfma_f32_16x16x32_f16(af0, ones, accS0, 0, 0, 0);
        acc10 = __builtin_amdgcn_mfma_f32_16x16x32_f16(af1, bb0, acc10, 0, 0, 0);
        acc11 = __builtin_amdgcn_mfma_f32_16x16x32_f16(af1, bb1, acc11, 0, 0, 0);
        accS1 = __builtin_amdgcn_mfma_f32_16x16x32_f16(af1, ones, accS1, 0, 0, 0);
    };

    unsigned wA0 = adjr0[0], wA1 = adjr1[0];
    half8 bA0 = *(const half8*)(hb);
    half8 bA1 = *(const half8*)(hb + 512);
    float4 eA0 = ed4[0], eA1 = ed4[1];
    float4 fA0 = ed54[0], fA1 = ed54[1];
    __builtin_amdgcn_sched_barrier(0);

#pragma unroll 1
    for (int p = 0; p < 8; ++p) {
        const int nB = 2 * p + 1;
        const unsigned wB0 = adjr0[(size_t)nB * NN];
        const unsigned wB1 = adjr1[(size_t)nB * NN];
        const half8 bB0 = *(const half8*)(hb + nB * 4096);
        const half8 bB1 = *(const half8*)(hb + nB * 4096 + 512);
        const float4 eB0 = ed4[nB * 8],  eB1 = ed4[nB * 8 + 1];
        const float4 fB0 = ed54[nB * 8], fB1 = ed54[nB * 8 + 1];
        __builtin_amdgcn_sched_barrier(0);

        COMPUTE(wA0, wA1, bA0, bA1, eA0, eA1, fA0, fA1);
        __builtin_amdgcn_sched_barrier(0);

        if (p < 7) {
            const int nA = 2 * p + 2;
            wA0 = adjr0[(size_t)nA * NN];
            wA1 = adjr1[(size_t)nA * NN];
            bA0 = *(const half8*)(hb + nA * 4096);
            bA1 = *(const half8*)(hb + nA * 4096 + 512);
            eA0 = ed4[nA * 8];  eA1 = ed4[nA * 8 + 1];
            fA0 = ed54[nA * 8]; fA1 = ed54[nA * 8 + 1];
        }
        __builtin_amdgcn_sched_barrier(0);

        COMPUTE(wB0, wB1, bB0, bB1, eB0, eB1, fB0, fB1);
        __builtin_amdgcn_sched_barrier(0);
    }

    const size_t prow0 = (size_t)(jq * BB + b) * NN + i0;
#pragma unroll
    for (int r = 0; r < 4; ++r) {
        const size_t row0 = prow0 + 4 * g + r;
        const size_t row1 = prow0 + 16 + 4 * g + r;
        P[row0 * HID + h * 32 + r16]      = (_Float16)acc00[r];
        P[row0 * HID + h * 32 + 16 + r16] = (_Float16)acc01[r];
        P[row1 * HID + h * 32 + r16]      = (_Float16)acc10[r];
        P[row1 * HID + h * 32 + 16 + r16] = (_Float16)acc11[r];
        if (r16 == 0) {
            S[row0 * HEADS + h] = accS0[r];
            S[row1 * HEADS + h] = accS1[r];
        }
    }
}

// Hidden-GEMM body (shared by fused phase A and fallback k_pre); needs 36 KB smem.
__device__ __forceinline__ void hidden_body(
    int hbid, int t, char* smem,
    const float* __restrict__ x, const float* __restrict__ W_in,
    const float* __restrict__ b_in, const float* __restrict__ att_src,
    const float* __restrict__ att_dst, _Float16* __restrict__ hHT,
    float* __restrict__ EsA, float* __restrict__ Es5A,
    float* __restrict__ EdA, float* __restrict__ Ed5A)
{
    float* Wl = (float*)smem;                          // 32 KB
    float (*xl)[CIN] = (float(*)[CIN])(smem + 32768);  // 4 KB
    const int jj0 = hbid * 16;
    {
        const float4* Ws = (const float4*)W_in;
        float4* Wd = (float4*)Wl;
#pragma unroll
        for (int u = 0; u < 8; ++u) Wd[t + 256 * u] = Ws[t + 256 * u];
        ((float4*)&xl[0][0])[t] = ((const float4*)(x + (size_t)jj0 * CIN))[t];
    }
    __syncthreads();

    const int c = t & 127, rg = t >> 7;
    const int b = jj0 >> 11, j0 = (jj0 & (NN - 1)) + rg * 8;
    const int h = c >> 5;

    float acc[8];
    const float bc = b_in[c];
#pragma unroll
    for (int rr = 0; rr < 8; ++rr) acc[rr] = bc;

#pragma unroll
    for (int k4 = 0; k4 < CIN; k4 += 4) {
        const float w0 = Wl[(k4 + 0) * HID + c];
        const float w1 = Wl[(k4 + 1) * HID + c];
        const float w2 = Wl[(k4 + 2) * HID + c];
        const float w3 = Wl[(k4 + 3) * HID + c];
#pragma unroll
        for (int rr = 0; rr < 8; ++rr) {
            const float4 xv = *(const float4*)&xl[rg * 8 + rr][k4];
            acc[rr] = fmaf(xv.w, w3, fmaf(xv.z, w2, fmaf(xv.y, w1, fmaf(xv.x, w0, acc[rr]))));
        }
    }

    half8 hv;
#pragma unroll
    for (int rr = 0; rr < 8; ++rr) hv[rr] = (_Float16)acc[rr];
    *(half8*)(hHT + (size_t)b * KTOT + (size_t)(j0 >> 5) * 4096 + c * 32 + (j0 & 31)) = hv;

    const float as = att_src[c], ad = att_dst[c];
#pragma unroll
    for (int rr = 0; rr < 8; ++rr) {
        float vs = acc[rr] * as, vd = acc[rr] * ad;
#pragma unroll
        for (int m = 16; m >= 1; m >>= 1) {
            vs += __shfl_xor(vs, m, 64);
            vd += __shfl_xor(vd, m, 64);
        }
        if ((t & 31) == 0) {
            const size_t idx = (size_t)(b * HEADS + h) * NN + j0 + rr;
            const float s2 = vs * LOG2E, d2 = vd * LOG2E;
            EsA[idx]  = __builtin_amdgcn_exp2f(s2);
            Es5A[idx] = __builtin_amdgcn_exp2f(0.2f * s2);
            EdA[idx]  = __builtin_amdgcn_exp2f(d2);
            Ed5A[idx] = __builtin_amdgcn_exp2f(0.2f * d2);
        }
    }
}

__device__ __forceinline__ void adjitem_body(int gid, int lane, const int* __restrict__ adj,
                                             unsigned* __restrict__ adjT)
{
    const int4* p = (const int4*)(adj + (size_t)gid * 8);
    const int4 a = p[0], b = p[1];
    unsigned byte =
        (a.x != 0 ? 1u : 0u)  | (a.y != 0 ? 2u : 0u)  | (a.z != 0 ? 4u : 0u)  | (a.w != 0 ? 8u : 0u) |
        (b.x != 0 ? 16u : 0u) | (b.y != 0 ? 32u : 0u) | (b.z != 0 ? 64u : 0u) | (b.w != 0 ? 128u : 0u);
    unsigned v = byte | (((unsigned)__shfl_xor((int)byte, 1, 64)) << 8);
    v = v | (((unsigned)__shfl_xor((int)v, 2, 64)) << 16);
    if ((lane & 3) == 0) {
        const int widx = gid >> 2;
        const int i = widx >> 6, jw = widx & 63;
        adjT[(size_t)jw * NN + i] = v;
    }
}

// Phase-C body for one virtual block id (R21 k_proj config); smem >= 17.7 KB
__device__ __forceinline__ void proj_body(
    int vb, int t, char* smem, const _Float16* __restrict__ P,
    const float* __restrict__ S, const float* __restrict__ W_out,
    float* __restrict__ dout)
{
    float (*wlT)[260] = (float(*)[260])smem;
    float* red = (float*)(smem + 16640);
    const int k0 = vb * 256;

#pragma unroll
    for (int u = 0; u < 4; ++u) {
        const int flat = (u * 256 + t) * 4;
        const float4 wv = *(const float4*)(W_out + (size_t)k0 * NQ + flat);
        const int krel = flat >> 4;
        const int q0 = flat & 15;
        wlT[q0 + 0][krel] = wv.x;
        wlT[q0 + 1][krel] = wv.y;
        wlT[q0 + 2][krel] = wv.z;
        wlT[q0 + 3][krel] = wv.w;
    }
    __syncthreads();

    const int q = t & 15;
    const int b = (t >> 4) & 3;
    const int ks = (t >> 6) * 64;
    const int i = (k0 + ks) >> 7;

    const _Float16* p0 = P + (size_t)(0 * BB + b) * KTOT + k0 + ks;
    const _Float16* p1 = P + (size_t)(1 * BB + b) * KTOT + k0 + ks;
    const _Float16* p2 = P + (size_t)(2 * BB + b) * KTOT + k0 + ks;
    const _Float16* p3 = P + (size_t)(3 * BB + b) * KTOT + k0 + ks;

    float acc = 0.f;
#pragma unroll
    for (int seg = 0; seg < 2; ++seg) {
        const int h = ((k0 + ks + seg * 32) >> 5) & 3;
        float rs = 0.f;
#pragma unroll
        for (int s = 0; s < NSL; ++s)
            rs += S[((size_t)(s * BB + b) * NN + i) * HEADS + h];
        const float inv = __builtin_amdgcn_rcpf(rs);
#pragma unroll
        for (int k8 = 0; k8 < 4; ++k8) {
            const int kk = seg * 32 + k8 * 8;
            const half8 a0 = *(const half8*)(p0 + kk);
            const half8 a1 = *(const half8*)(p1 + kk);
            const half8 a2 = *(const half8*)(p2 + kk);
            const half8 a3 = *(const half8*)(p3 + kk);
            const float4 w0 = *(const float4*)&wlT[q][ks + kk];
            const float4 w1 = *(const float4*)&wlT[q][ks + kk + 4];
            const float wf[8] = {w0.x, w0.y, w0.z, w0.w, w1.x, w1.y, w1.z, w1.w};
#pragma unroll
            for (int e = 0; e < 8; ++e) {
                const float ev = ((float)a0[e] + (float)a1[e]) + ((float)a2[e] + (float)a3[e]);
                acc = fmaf(ev * inv, wf[e], acc);
            }
        }
    }

    red[t] = acc;
    __syncthreads();
    if (t < 64)
        atomicAdd(&dout[t], red[t] + red[t + 64] + red[t + 128] + red[t + 192]);
    __syncthreads();   // red/wlT reused by caller's next round
}

// ===================== fused cooperative kernel (GRID=512) =====================
__global__ __launch_bounds__(256, 4) void k_fused(
    const float* __restrict__ x, const float* __restrict__ W_in,
    const float* __restrict__ b_in, const float* __restrict__ att_src,
    const float* __restrict__ att_dst, const int* __restrict__ adj,
    const float* __restrict__ W_out, const float* __restrict__ b_out,
    _Float16* __restrict__ hHT, float* __restrict__ EsA, float* __restrict__ Es5A,
    float* __restrict__ EdA, float* __restrict__ Ed5A, unsigned* __restrict__ adjT,
    _Float16* __restrict__ P, float* __restrict__ S, float* __restrict__ dout)
{
    cg::grid_group grid = cg::this_grid();
    __shared__ __align__(16) char smem[36864];
    const int t = threadIdx.x;
    const int bid = blockIdx.x;
    const int lane = t & 63;

    // Phase A: hidden on all 512 blocks; adj 4 items/thread; bias init by block 0
    hidden_body(bid, t, smem, x, W_in, b_in, att_src, att_dst, hHT, EsA, Es5A, EdA, Ed5A);
#pragma unroll
    for (int u = 0; u < 4; ++u)
        adjitem_body(bid * 1024 + u * 256 + t, lane, adj, adjT);
    if (bid == 0 && t < 64) dout[t] = b_out[t & 15];

    grid.sync();

    // Phase B: two virtual blocks per real block
    attn_body(bid,       t, adjT, hHT, EsA, Es5A, EdA, Ed5A, P, S);
    attn_body(bid + 512, t, adjT, hHT, EsA, Es5A, EdA, Ed5A, P, S);

    grid.sync();

    // Phase C: two virtual blocks per real block (LDS aliased)
    proj_body(bid,       t, smem, P, S, W_out, dout);
    proj_body(bid + 512, t, smem, P, S, W_out, dout);
}

// ===================== fallback kernels (R21 three-launch path) =====================
__global__ __launch_bounds__(256) void kf_pre(
    const float* __restrict__ x, const float* __restrict__ W_in,
    const float* __restrict__ b_in, const float* __restrict__ att_src,
    const float* __restrict__ att_dst, const int* __restrict__ adj,
    _Float16* __restrict__ hHT, float* __restrict__ EsA, float* __restrict__ Es5A,
    float* __restrict__ EdA, float* __restrict__ Ed5A,
    unsigned* __restrict__ adjT, const float* __restrict__ b_out,
    float* __restrict__ dout)
{
    __shared__ __align__(16) char smem[36864];
    const int t = threadIdx.x;
    if (blockIdx.x >= HB) {
        const int bid = blockIdx.x - HB;
        if (bid == 0 && t < 64) dout[t] = b_out[t & 15];
        adjitem_body(bid * 256 + t, t & 63, adj, adjT);
        return;
    }
    hidden_body(blockIdx.x, t, smem, x, W_in, b_in, att_src, att_dst, hHT, EsA, Es5A, EdA, Ed5A);
}

__global__ __launch_bounds__(256, 4) void kf_attn(
    const unsigned* __restrict__ adjT, const _Float16* __restrict__ hHT,
    const float* __restrict__ EsA, const float* __restrict__ Es5A,
    const float* __restrict__ EdA, const float* __restrict__ Ed5A,
    _Float16* __restrict__ P, float* __restrict__ S)
{
    attn_body(blockIdx.x, threadIdx.x, adjT, hHT, EsA, Es5A, EdA, Ed5A, P, S);
}

__global__ __launch_bounds__(256) void kf_proj(
    const _Float16* __restrict__ P, const float* __restrict__ S,
    const float* __restrict__ W_out, float* __restrict__ dout)
{
    __shared__ __align__(16) char smem[17664];
    proj_body(blockIdx.x, threadIdx.x, smem, P, S, W_out, dout);
}

extern "C" void kernel_launch(void* const* d_in, const int* in_sizes, int n_in,
                              void* d_out, int out_size, void* d_ws, size_t ws_size,
                              hipStream_t stream)
{
    const float* x       = (const float*)d_in[0];
    const int*   adj     = (const int*)d_in[1];
    const float* W_in    = (const float*)d_in[2];
    const float* b_in    = (const float*)d_in[3];
    const float* att_src = (const float*)d_in[4];
    const float* att_dst = (const float*)d_in[5];
    const float* W_out   = (const float*)d_in[6];
    const float* b_out   = (const float*)d_in[7];
    float* out = (float*)d_out;

    char* ws = (char*)d_ws;
    _Float16* P = (_Float16*)ws;                                     // 8.4 MB
    float* S    = (float*)(ws + sizeof(_Float16) * (size_t)NSL * BB * KTOT);  // 512 KB
    float* EsA  = S + (size_t)NSL * BB * NN * HEADS;                 // 128 KB each
    float* Es5A = EsA  + (size_t)BB * HEADS * NN;
    float* EdA  = Es5A + (size_t)BB * HEADS * NN;
    float* Ed5A = EdA  + (size_t)BB * HEADS * NN;
    _Float16* hHT = (_Float16*)(Ed5A + (size_t)BB * HEADS * NN);     // 2 MB
    unsigned* adjT = (unsigned*)((char*)hHT + sizeof(_Float16) * (size_t)BB * KTOT); // 512 KB

    // capability gate (host-only queries; capture-safe)
    static int coop_ok = -1;
    if (coop_ok < 0) {
        int dev = 0; hipGetDevice(&dev);
        int coop = 0, ncu = 0, mb = 0;
        hipDeviceGetAttribute(&coop, hipDeviceAttributeCooperativeLaunch, dev);
        hipDeviceGetAttribute(&ncu, hipDeviceAttributeMultiprocessorCount, dev);
        hipOccupancyMaxActiveBlocksPerMultiprocessor(&mb, (const void*)k_fused, 256, 0);
        coop_ok = (coop && (long)mb * ncu >= GRID) ? 1 : 0;
    }

    bool done = false;
    if (coop_ok == 1) {
        const float* xx = x; const float* wi = W_in; const float* bi = b_in;
        const float* as_ = att_src; const float* ad_ = att_dst; const int* aj = adj;
        const float* wo = W_out; const float* bo = b_out;
        _Float16* hh = hHT; float* e1 = EsA; float* e2 = Es5A; float* e3 = EdA; float* e4 = Ed5A;
        unsigned* at = adjT; _Float16* pp = P; float* ss = S; float* oo = out;
        void* kargs[] = {
            &xx, &wi, &bi, &as_, &ad_, &aj, &wo, &bo,
            &hh, &e1, &e2, &e3, &e4, &at, &pp, &ss, &oo
        };
        hipError_t e = hipLaunchCooperativeKernel((void*)k_fused, dim3(GRID), dim3(256),
                                                  kargs, 0, stream);
        if (e == hipSuccess) done = true;
        else coop_ok = 0;   // deterministic fallback for all future calls
    }

    if (!done) {
        kf_pre<<<HB + AB, 256, 0, stream>>>(x, W_in, b_in, att_src, att_dst, adj,
                                            hHT, EsA, Es5A, EdA, Ed5A, adjT, b_out, out);
        kf_attn<<<NSL * BB * (NN / 32), 256, 0, stream>>>(adjT, hHT, EsA, Es5A, EdA, Ed5A, P, S);
        kf_proj<<<KTOT / 256, 256, 0, stream>>>(P, S, W_out, out);
    }
}

// Round 24
// 70.733 us; speedup vs baseline: 2.7940x; 2.7940x over previous
//
#include <hip/hip_runtime.h>
#include <math.h>

#define BB 4
#define NN 2048
#define CIN 64
#define HID 128
#define HEADS 4
#define NQ 16
#define KTOT (NN*HID) // 262144
#define LOG2E 1.44269504088896340736f
#define NEGBIG_BITS 0xC2C80000u   // -100.0f
#define NSL 4         // j-slices (512 j each)
#define HB 512        // k_pre blocks doing hidden (16 rows each)
#define AB 2048       // k_pre blocks doing adj bitmask

typedef __attribute__((ext_vector_type(8))) _Float16 half8;
typedef __attribute__((ext_vector_type(4))) float f32x4;
typedef __attribute__((ext_vector_type(4))) unsigned uint4v;

// ---------------- k_pre: hidden GEMM (blocks 0..511) + adj bitmask (blocks 512..2559) ----
// hidden -> TILED hHT[b][jblk][d][j32] f16, alphas pre-scaled log2e; adj -> TRANSPOSED adjT[jw][i].
__global__ __launch_bounds__(256) void k_pre(
    const float* __restrict__ x, const float* __restrict__ W_in,
    const float* __restrict__ b_in, const float* __restrict__ att_src,
    const float* __restrict__ att_dst, const int* __restrict__ adj,
    _Float16* __restrict__ hHT, float* __restrict__ srcA, float* __restrict__ dstA,
    unsigned* __restrict__ adjT, const float* __restrict__ b_out,
    float* __restrict__ dout)
{
    __shared__ float Wl[CIN * HID];   // 32 KB
    __shared__ float xl[16][CIN];     // 4 KB
    const int t = threadIdx.x;

    if (blockIdx.x >= HB) {
        // ---- adj -> transposed bitmask; first adj-block inits d_out ----
        const int bid = blockIdx.x - HB;
        if (bid == 0 && t < 64) dout[t] = b_out[t & 15];
        const int gid = bid * 256 + t;              // 0 .. N*N/8-1
        const int lane = t & 63;
        const int4* p = (const int4*)(adj + (size_t)gid * 8);
        const int4 a = p[0], b = p[1];
        unsigned byte =
            (a.x != 0 ? 1u : 0u)  | (a.y != 0 ? 2u : 0u)  | (a.z != 0 ? 4u : 0u)  | (a.w != 0 ? 8u : 0u) |
            (b.x != 0 ? 16u : 0u) | (b.y != 0 ? 32u : 0u) | (b.z != 0 ? 64u : 0u) | (b.w != 0 ? 128u : 0u);
        unsigned u = byte | (((unsigned)__shfl_xor((int)byte, 1, 64)) << 8);
        u = u | (((unsigned)__shfl_xor((int)u, 2, 64)) << 16);
        if ((lane & 3) == 0) {
            const int widx = gid >> 2;                 // = i*64 + jw
            const int i = widx >> 6, jw = widx & 63;
            adjT[(size_t)jw * NN + i] = u;             // transposed
        }
        return;
    }

    // ---- hidden: 16 rows per block ----
    const int jj0 = blockIdx.x * 16;
    {
        const float4* Ws = (const float4*)W_in;
        float4* Wd = (float4*)Wl;
#pragma unroll
        for (int u = 0; u < 8; ++u) Wd[t + 256 * u] = Ws[t + 256 * u];
        ((float4*)&xl[0][0])[t] = ((const float4*)(x + (size_t)jj0 * CIN))[t];
    }
    __syncthreads();

    const int c = t & 127, rg = t >> 7;
    const int b = jj0 >> 11, j0 = (jj0 & (NN - 1)) + rg * 8;
    const int h = c >> 5;

    float acc[8];
    const float bc = b_in[c];
#pragma unroll
    for (int rr = 0; rr < 8; ++rr) acc[rr] = bc;

#pragma unroll
    for (int k4 = 0; k4 < CIN; k4 += 4) {
        const float w0 = Wl[(k4 + 0) * HID + c];
        const float w1 = Wl[(k4 + 1) * HID + c];
        const float w2 = Wl[(k4 + 2) * HID + c];
        const float w3 = Wl[(k4 + 3) * HID + c];
#pragma unroll
        for (int rr = 0; rr < 8; ++rr) {
            const float4 xv = *(const float4*)&xl[rg * 8 + rr][k4];
            acc[rr] = fmaf(xv.w, w3, fmaf(xv.z, w2, fmaf(xv.y, w1, fmaf(xv.x, w0, acc[rr]))));
        }
    }

    half8 hv;
#pragma unroll
    for (int rr = 0; rr < 8; ++rr) hv[rr] = (_Float16)acc[rr];
    // tiled store: [b][jblk=j0>>5][d=c][j0&31 .. +8)
    *(half8*)(hHT + (size_t)b * KTOT + (size_t)(j0 >> 5) * 4096 + c * 32 + (j0 & 31)) = hv;

    const float as = att_src[c], ad = att_dst[c];
#pragma unroll
    for (int rr = 0; rr < 8; ++rr) {
        float vs = acc[rr] * as, vd = acc[rr] * ad;
#pragma unroll
        for (int m = 16; m >= 1; m >>= 1) {
            vs += __shfl_xor(vs, m, 64);
            vd += __shfl_xor(vd, m, 64);
        }
        if ((t & 31) == 0) {
            srcA[(size_t)(b * HEADS + h) * NN + j0 + rr] = vs * LOG2E;
            dstA[(size_t)(b * HEADS + h) * NN + j0 + rr] = vd * LOG2E;
        }
    }
}

// ---------------- k_attn: register flash-GAT, i-tile 32, fenced depth-1 prefetch --------
__global__ __launch_bounds__(256, 4) void k_attn(
    const unsigned* __restrict__ adjT, const _Float16* __restrict__ hHT,
    const float* __restrict__ srcA, const float* __restrict__ dstA,
    _Float16* __restrict__ P, float* __restrict__ S)
{
    const int t = threadIdx.x;
    const int lane = t & 63;
    const int h = t >> 6;                // wave id = head
    const int bx = blockIdx.x;
    const int iq = bx & 63;
    const int b = (bx >> 6) & 3;
    const int jq = bx >> 8;
    const int i0 = iq * 32;
    const int jb0 = jq * 16;             // first 32-j block of this wave's 512-j slice

    const int r16 = lane & 15;
    const int g = lane >> 4;

    const float srci0 = srcA[(size_t)(b * HEADS + h) * NN + i0 + r16];
    const float srci1 = srcA[(size_t)(b * HEADS + h) * NN + i0 + 16 + r16];
    const unsigned* adjr0 = adjT + (size_t)jb0 * NN + i0 + r16;                // +n*NN
    const unsigned* adjr1 = adjr0 + 16;
    const _Float16* hb = hHT + (size_t)b * KTOT + (size_t)jb0 * 4096
                             + (h * 32 + r16) * 32 + g * 8;                    // +n*4096
    const float4* dst4 = (const float4*)(dstA + (size_t)(b * HEADS + h) * NN + jq * 512) + 2 * g;

    f32x4 acc00 = {0.f, 0.f, 0.f, 0.f};   // frag0 (i0..i0+15), d lo16
    f32x4 acc01 = {0.f, 0.f, 0.f, 0.f};   // frag0, d hi16
    f32x4 acc10 = {0.f, 0.f, 0.f, 0.f};   // frag1 (i0+16..31), d lo16
    f32x4 acc11 = {0.f, 0.f, 0.f, 0.f};   // frag1, d hi16
    f32x4 accS0 = {0.f, 0.f, 0.f, 0.f};
    f32x4 accS1 = {0.f, 0.f, 0.f, 0.f};
    const half8 ones = {(_Float16)1.f, (_Float16)1.f, (_Float16)1.f, (_Float16)1.f,
                        (_Float16)1.f, (_Float16)1.f, (_Float16)1.f, (_Float16)1.f};

    // weights for one i-frag from adj bits + dst values (log2-scaled)
    auto MAKEAF = [&](float srci, unsigned bits, const float* dvv) -> half8 {
        float wv[8];
#pragma unroll
        for (int e = 0; e < 8; ++e) {
            float s = srci + dvv[e];
            s = fmaxf(s, 0.2f * s);                                   // leaky relu
            const unsigned m = (unsigned)(((int)(bits << (31 - e))) >> 31);
            const unsigned su = __builtin_bit_cast(unsigned, s);
            wv[e] = __builtin_amdgcn_exp2f(
                __builtin_bit_cast(float, (su & m) | (NEGBIG_BITS & ~m)));
        }
        uint4v uu;
        uu[0] = __builtin_bit_cast(unsigned, __builtin_amdgcn_cvt_pkrtz(wv[0], wv[1]));
        uu[1] = __builtin_bit_cast(unsigned, __builtin_amdgcn_cvt_pkrtz(wv[2], wv[3]));
        uu[2] = __builtin_bit_cast(unsigned, __builtin_amdgcn_cvt_pkrtz(wv[4], wv[5]));
        uu[3] = __builtin_bit_cast(unsigned, __builtin_amdgcn_cvt_pkrtz(wv[6], wv[7]));
        return __builtin_bit_cast(half8, uu);
    };

    auto COMPUTE = [&](unsigned w0, unsigned w1, half8 bb0, half8 bb1,
                       float4 dv0, float4 dv1) {
        const float dvv[8] = {dv0.x, dv0.y, dv0.z, dv0.w, dv1.x, dv1.y, dv1.z, dv1.w};
        const half8 af0 = MAKEAF(srci0, w0 >> (8 * g), dvv);
        const half8 af1 = MAKEAF(srci1, w1 >> (8 * g), dvv);
        acc00 = __builtin_amdgcn_mfma_f32_16x16x32_f16(af0, bb0, acc00, 0, 0, 0);
        acc01 = __builtin_amdgcn_mfma_f32_16x16x32_f16(af0, bb1, acc01, 0, 0, 0);
        accS0 = __builtin_amdgcn_mfma_f32_16x16x32_f16(af0, ones, accS0, 0, 0, 0);
        acc10 = __builtin_amdgcn_mfma_f32_16x16x32_f16(af1, bb0, acc10, 0, 0, 0);
        acc11 = __builtin_amdgcn_mfma_f32_16x16x32_f16(af1, bb1, acc11, 0, 0, 0);
        accS1 = __builtin_amdgcn_mfma_f32_16x16x32_f16(af1, ones, accS1, 0, 0, 0);
    };

    // prime buffer A (iteration 0)
    unsigned wA0 = adjr0[0], wA1 = adjr1[0];
    half8 bA0 = *(const half8*)(hb);
    half8 bA1 = *(const half8*)(hb + 512);
    float4 dA0 = dst4[0], dA1 = dst4[1];
    __builtin_amdgcn_sched_barrier(0);

#pragma unroll 1
    for (int p = 0; p < 8; ++p) {
        const int nB = 2 * p + 1;
        // prefetch buffer B (iteration nB) — fenced so it stays here
        const unsigned wB0 = adjr0[(size_t)nB * NN];
        const unsigned wB1 = adjr1[(size_t)nB * NN];
        const half8 bB0 = *(const half8*)(hb + nB * 4096);
        const half8 bB1 = *(const half8*)(hb + nB * 4096 + 512);
        const float4 dB0 = dst4[nB * 8], dB1 = dst4[nB * 8 + 1];
        __builtin_amdgcn_sched_barrier(0);

        COMPUTE(wA0, wA1, bA0, bA1, dA0, dA1);       // iter 2p, B-loads in flight
        __builtin_amdgcn_sched_barrier(0);

        if (p < 7) {                                  // prefetch buffer A (iter 2p+2)
            const int nA = 2 * p + 2;
            wA0 = adjr0[(size_t)nA * NN];
            wA1 = adjr1[(size_t)nA * NN];
            bA0 = *(const half8*)(hb + nA * 4096);
            bA1 = *(const half8*)(hb + nA * 4096 + 512);
            dA0 = dst4[nA * 8]; dA1 = dst4[nA * 8 + 1];
        }
        __builtin_amdgcn_sched_barrier(0);

        COMPUTE(wB0, wB1, bB0, bB1, dB0, dB1);       // iter 2p+1, A-loads in flight
        __builtin_amdgcn_sched_barrier(0);
    }

    // direct store of both frags (verified layout: i = 4g+r, d = r16); P f16
    const size_t prow0 = (size_t)(jq * BB + b) * NN + i0;
#pragma unroll
    for (int r = 0; r < 4; ++r) {
        const size_t row0 = prow0 + 4 * g + r;
        const size_t row1 = prow0 + 16 + 4 * g + r;
        P[row0 * HID + h * 32 + r16]      = (_Float16)acc00[r];
        P[row0 * HID + h * 32 + 16 + r16] = (_Float16)acc01[r];
        P[row1 * HID + h * 32 + r16]      = (_Float16)acc10[r];
        P[row1 * HID + h * 32 + 16 + r16] = (_Float16)acc11[r];
        if (r16 == 0) {
            S[row0 * HEADS + h] = accS0[r];
            S[row1 * HEADS + h] = accS1[r];
        }
    }
}

// ---------------- k_proj: combine 4 f16 partials + projection (W^T in LDS) --------------
__global__ __launch_bounds__(256) void k_proj(
    const _Float16* __restrict__ P, const float* __restrict__ S,
    const float* __restrict__ W_out, float* __restrict__ dout)
{
    __shared__ float wlT[NQ][260];     // 16.6 KB
    __shared__ float red[256];

    const int t = threadIdx.x;
    const int k0 = blockIdx.x * 256;

#pragma unroll
    for (int u = 0; u < 4; ++u) {
        const int flat = (u * 256 + t) * 4;
        const float4 wv = *(const float4*)(W_out + (size_t)k0 * NQ + flat);
        const int krel = flat >> 4;
        const int q0 = flat & 15;
        wlT[q0 + 0][krel] = wv.x;
        wlT[q0 + 1][krel] = wv.y;
        wlT[q0 + 2][krel] = wv.z;
        wlT[q0 + 3][krel] = wv.w;
    }
    __syncthreads();

    const int q = t & 15;
    const int b = (t >> 4) & 3;
    const int ks = (t >> 6) * 64;
    const int i = (k0 + ks) >> 7;

    const _Float16* p0 = P + (size_t)(0 * BB + b) * KTOT + k0 + ks;
    const _Float16* p1 = P + (size_t)(1 * BB + b) * KTOT + k0 + ks;
    const _Float16* p2 = P + (size_t)(2 * BB + b) * KTOT + k0 + ks;
    const _Float16* p3 = P + (size_t)(3 * BB + b) * KTOT + k0 + ks;

    float acc = 0.f;
#pragma unroll
    for (int seg = 0; seg < 2; ++seg) {
        const int h = ((k0 + ks + seg * 32) >> 5) & 3;
        float rs = 0.f;
#pragma unroll
        for (int s = 0; s < NSL; ++s)
            rs += S[((size_t)(s * BB + b) * NN + i) * HEADS + h];
        const float inv = __builtin_amdgcn_rcpf(rs);
#pragma unroll
        for (int k8 = 0; k8 < 4; ++k8) {
            const int kk = seg * 32 + k8 * 8;
            const half8 a0 = *(const half8*)(p0 + kk);
            const half8 a1 = *(const half8*)(p1 + kk);
            const half8 a2 = *(const half8*)(p2 + kk);
            const half8 a3 = *(const half8*)(p3 + kk);
            const float4 w0 = *(const float4*)&wlT[q][ks + kk];
            const float4 w1 = *(const float4*)&wlT[q][ks + kk + 4];
            const float wf[8] = {w0.x, w0.y, w0.z, w0.w, w1.x, w1.y, w1.z, w1.w};
#pragma unroll
            for (int e = 0; e < 8; ++e) {
                const float ev = ((float)a0[e] + (float)a1[e]) + ((float)a2[e] + (float)a3[e]);
                acc = fmaf(ev * inv, wf[e], acc);
            }
        }
    }

    red[t] = acc;
    __syncthreads();
    if (t < 64)
        atomicAdd(&dout[t], red[t] + red[t + 64] + red[t + 128] + red[t + 192]);
}

extern "C" void kernel_launch(void* const* d_in, const int* in_sizes, int n_in,
                              void* d_out, int out_size, void* d_ws, size_t ws_size,
                              hipStream_t stream)
{
    const float* x       = (const float*)d_in[0];
    const int*   adj     = (const int*)d_in[1];
    const float* W_in    = (const float*)d_in[2];
    const float* b_in    = (const float*)d_in[3];
    const float* att_src = (const float*)d_in[4];
    const float* att_dst = (const float*)d_in[5];
    const float* W_out   = (const float*)d_in[6];
    const float* b_out   = (const float*)d_in[7];
    float* out = (float*)d_out;

    char* ws = (char*)d_ws;
    _Float16* P = (_Float16*)ws;                                     // NSL*BB*KTOT f16 = 8.4 MB
    float* S    = (float*)(ws + sizeof(_Float16) * (size_t)NSL * BB * KTOT);  // 512 KB
    float* srcA = S + (size_t)NSL * BB * NN * HEADS;                 // 128 KB
    float* dstA = srcA + (size_t)BB * HEADS * NN;                    // 128 KB
    _Float16* hHT = (_Float16*)(dstA + (size_t)BB * HEADS * NN);     // 2 MB (tiled)
    unsigned* adjT = (unsigned*)((char*)hHT + sizeof(_Float16) * (size_t)BB * KTOT); // 512 KB

    k_pre<<<HB + AB, 256, 0, stream>>>(x, W_in, b_in, att_src, att_dst, adj,
                                       hHT, srcA, dstA, adjT, b_out, out);
    // block = (iq 64, b 4, jq 4) -> 1024 blocks x 4 waves
    k_attn<<<NSL * BB * (NN / 32), 256, 0, stream>>>(adjT, hHT, srcA, dstA, P, S);
    k_proj<<<KTOT / 256, 256, 0, stream>>>(P, S, W_out, out);
}